// Round 1
// 273.284 us; speedup vs baseline: 1.0185x; 1.0185x over previous
//
#include <hip/hip_runtime.h>
#include <math.h>

// Problem constants (fixed by reference file)
#define NB   2
#define LQ   16384
#define CDIM 256
#define MH   8          // heads
#define DH   32         // head dim
#define LIN  21760      // 128^2+64^2+32^2+16^2

typedef __attribute__((ext_vector_type(8))) _Float16 f16x8;
typedef __attribute__((ext_vector_type(4))) _Float16 f16x4;
typedef __attribute__((ext_vector_type(4))) float    f32x4;

// async 16B global->LDS (wave-uniform LDS base + lane*16 — no padding allowed)
__device__ __forceinline__ void async16(const void* g, void* l) {
    __builtin_amdgcn_global_load_lds(
        (const __attribute__((address_space(1))) void*)g,
        (__attribute__((address_space(3))) void*)l,
        16, 0, 0);
}

// ---------------- f32 -> f16 plane (GEMM A-operands) ----------------
__global__ __launch_bounds__(256) void split_f16_kernel(
    const float* __restrict__ in, _Float16* __restrict__ o, int n8)
{
    const int i = blockIdx.x * 256 + threadIdx.x;
    if (i >= n8) return;
    const float4 v0 = ((const float4*)in)[i * 2];
    const float4 v1 = ((const float4*)in)[i * 2 + 1];
    f16x8 h;
    h[0] = (_Float16)v0.x; h[1] = (_Float16)v0.y;
    h[2] = (_Float16)v0.z; h[3] = (_Float16)v0.w;
    h[4] = (_Float16)v1.x; h[5] = (_Float16)v1.y;
    h[6] = (_Float16)v1.z; h[7] = (_Float16)v1.w;
    ((f16x8*)o)[i] = h;
}

// transpose weights to f16: W[k][n] f32 -> out[n][k] f16
__global__ __launch_bounds__(256) void tsplit_f16_kernel(
    const float* __restrict__ W, _Float16* __restrict__ t, int N)
{
    const int i = blockIdx.x * 256 + threadIdx.x;
    if (i >= N * 256) return;
    const int nn = i >> 8;
    const int kk = i & 255;
    t[i] = (_Float16)W[kk * N + nn];
}

// ---------------- single-term f16 MFMA GEMM, routed epilogue ----------------
// C = A @ B + bias. A: MxK f16 row-major. Bt: [N][K] f16 (pre-transposed).
// Tile 128x128x32, 256 threads, 16 mfma_f32_16x16x32_f16 per iter.
// Output routing: cols < N0 -> C0 (ld N0, bias0); cols >= N0 -> C1 (ld N-N0, bias1).
// OUT_F16: write f16, else f32.
template <bool OUT_F16>
__global__ __launch_bounds__(256) void gemm_f16(
    const _Float16* __restrict__ A, const _Float16* __restrict__ Bt,
    const float* __restrict__ bias0, const float* __restrict__ bias1,
    void* __restrict__ C0, void* __restrict__ C1,
    int M, int N, int K, int N0)
{
    __shared__ _Float16 Ash[128 * 32];   // [row][k], unpadded (global_load_lds)
    __shared__ _Float16 Bsh[128 * 32];   // [n][k]

    const int tid  = threadIdx.x;
    const int wave = tid >> 6, lane = tid & 63;
    const int quad = lane >> 4, l16 = lane & 15;
    const int bm = blockIdx.y * 128;
    const int bn = blockIdx.x * 128;
    const int wrow = wave * 32;

    f32x4 acc[2][8] = {};

    const int s0 = tid,        row0 = s0 >> 2, kg0 = (s0 & 3) << 3;
    const int s1 = tid + 256,  row1 = s1 >> 2, kg1 = (s1 & 3) << 3;

    for (int k0 = 0; k0 < K; k0 += 32) {
        async16(A  + (size_t)(bm + row0) * K + k0 + kg0, Ash + s0 * 8);
        async16(A  + (size_t)(bm + row1) * K + k0 + kg1, Ash + s1 * 8);
        async16(Bt + (size_t)(bn + row0) * K + k0 + kg0, Bsh + s0 * 8);
        async16(Bt + (size_t)(bn + row1) * K + k0 + kg1, Bsh + s1 * 8);
        __syncthreads();

        f16x8 ah[2];
        #pragma unroll
        for (int r = 0; r < 2; ++r)
            ah[r] = *(const f16x8*)&Ash[(wrow + r * 16 + l16) * 32 + quad * 8];
        #pragma unroll
        for (int half = 0; half < 2; ++half) {
            f16x8 bh[4];
            #pragma unroll
            for (int c = 0; c < 4; ++c)
                bh[c] = *(const f16x8*)&Bsh[(half * 64 + c * 16 + l16) * 32 + quad * 8];
            #pragma unroll
            for (int r = 0; r < 2; ++r)
                #pragma unroll
                for (int c = 0; c < 4; ++c)
                    acc[r][half * 4 + c] = __builtin_amdgcn_mfma_f32_16x16x32_f16(
                        ah[r], bh[c], acc[r][half * 4 + c], 0, 0, 0);
        }
        __syncthreads();
    }

    // epilogue: C/D layout col=lane&15, row=quad*4+reg (HW-verified mapping)
    void* Cb; const float* bb; int ldc, coff;
    if (bn < N0) { Cb = C0; bb = bias0; ldc = N0;     coff = 0;  }
    else         { Cb = C1; bb = bias1; ldc = N - N0; coff = N0; }
    #pragma unroll
    for (int c = 0; c < 8; ++c) {
        const int col = bn + c * 16 + l16 - coff;
        const float bia = bb[col];
        #pragma unroll
        for (int r = 0; r < 2; ++r)
            #pragma unroll
            for (int i = 0; i < 4; ++i) {
                const int rr = bm + wrow + r * 16 + quad * 4 + i;
                const float v = acc[r][c][i] + bia;
                if (OUT_F16) ((_Float16*)Cb)[(size_t)rr * ldc + col] = (_Float16)v;
                else         ((float*)Cb)[(size_t)rr * ldc + col] = v;
            }
    }
}

// ---------------- softmax over last-16, in place ----------------
__global__ __launch_bounds__(256) void softmax16_kernel(float* __restrict__ a, int rows)
{
    const int r = blockIdx.x * 256 + threadIdx.x;
    if (r >= rows) return;
    float* row = a + (size_t)r * 16;
    float v[16];
    float4* rv = (float4*)row;
    #pragma unroll
    for (int i = 0; i < 4; ++i) *(float4*)&v[i * 4] = rv[i];
    float mx = v[0];
    #pragma unroll
    for (int i = 1; i < 16; ++i) mx = fmaxf(mx, v[i]);
    float s = 0.f;
    #pragma unroll
    for (int i = 0; i < 16; ++i) { v[i] = __expf(v[i] - mx); s += v[i]; }
    const float inv = 1.f / s;
    #pragma unroll
    for (int i = 0; i < 16; ++i) v[i] *= inv;
    #pragma unroll
    for (int i = 0; i < 4; ++i) rv[i] = *(float4*)&v[i * 4];
}

// ---------------- sampling v7: v6 structure, f16 VALUE taps ----------------
// Block = 256 threads, 4 queries.
// Phase 1: 512 tasks (q,m,pt) -> LDS: 4 combined corner weights + 4 indices.
// Phase 2: thread (q,m,d4) owns 4 channels; gathers f16x4 (8 B/lane — halves
//   the L2 read bytes vs f32: the measured bottleneck at 27 TB/s of L2 reads),
//   converts to f32, FMA-accumulates in f32, writes f16.
// Reference quirk preserved: sample (l,p) weighted by attn[..., p, l].
__global__ __launch_bounds__(256) void sample_kernel_v7(
    const _Float16* __restrict__ value,  // (N*LIN, 256) f16
    const float* __restrict__ off,       // (N*LQ, 256)
    const float* __restrict__ attn,      // (N*LQ, 128) softmaxed
    _Float16* __restrict__ outv)
{
    __shared__ __align__(16) float lds_task[8][516];

    const int tid = threadIdx.x;
    const int qbase = blockIdx.x * 4;

    #pragma unroll
    for (int j = 0; j < 2; ++j) {
        const int t  = tid + 256 * j;
        const int q  = t >> 7;
        const int m  = (t >> 4) & 7;
        const int pt = t & 15;          // pt = l*4 + p
        const int l  = pt >> 2;
        const int p  = pt & 3;
        const int qi = qbase + q;
        const int lq = qi & (LQ - 1);
        const int n  = qi >> 14;

        const int Hl = 128 >> l;
        const int STARTS[4] = {0, 16384, 20480, 21504};

        const float2 oxy = *(const float2*)&off[(size_t)qi * 256 + m * 32 + pt * 2];
        const float w    = attn[(size_t)qi * 128 + m * 16 + p * 4 + l]; // transposed pairing

        const float refx = ((lq & 127) + 0.5f) * (1.0f / 128.0f);
        const float refy = ((lq >> 7)  + 0.5f) * (1.0f / 128.0f);

        const float x = refx * (float)Hl + oxy.x - 0.5f;
        const float y = refy * (float)Hl + oxy.y - 0.5f;
        const float x0f = floorf(x), y0f = floorf(y);
        const int x0 = (int)x0f, y0 = (int)y0f;
        const int x1 = x0 + 1,  y1 = y0 + 1;
        const float fx = x - x0f, fy = y - y0f;
        const float gx = 1.f - fx, gy = 1.f - fy;

        const float vx0 = (x0 >= 0 && x0 < Hl) ? 1.f : 0.f;
        const float vx1 = (x1 >= 0 && x1 < Hl) ? 1.f : 0.f;
        const float vy0 = (y0 >= 0 && y0 < Hl) ? 1.f : 0.f;
        const float vy1 = (y1 >= 0 && y1 < Hl) ? 1.f : 0.f;

        const int x0c = min(max(x0, 0), Hl - 1);
        const int x1c = min(max(x1, 0), Hl - 1);
        const int y0c = min(max(y0, 0), Hl - 1);
        const int y1c = min(max(y1, 0), Hl - 1);

        const int base = (n * LIN + STARTS[l]) * 256 + m * 32;
        const int i00 = base + (y0c * Hl + x0c) * 256;
        const int i01 = base + (y0c * Hl + x1c) * 256;
        const int i10 = base + (y1c * Hl + x0c) * 256;
        const int i11 = base + (y1c * Hl + x1c) * 256;

        float4 wv;
        wv.x = w * gy * gx * vy0 * vx0;
        wv.y = w * gy * fx * vy0 * vx1;
        wv.z = w * fy * gx * vy1 * vx0;
        wv.w = w * fy * fx * vy1 * vx1;

        float* dst = &lds_task[m][(q * 16 + pt) * 8];
        *(float4*)dst = wv;
        int4 iv = {i00, i01, i10, i11};
        *(int4*)(dst + 4) = iv;
    }
    __syncthreads();

    // ---- Phase 2: gather f16 taps + weighted accumulate ----
    const int q  = tid >> 6;
    const int m  = (tid >> 3) & 7;
    const int d4 = tid & 7;
    const int qi = qbase + q;

    const _Float16* vbase = value + d4 * 4;

    float4 acc = {0.f, 0.f, 0.f, 0.f};
    #pragma unroll
    for (int pt = 0; pt < 16; ++pt) {
        const float* td = &lds_task[m][(q * 16 + pt) * 8];
        const float4 wv = *(const float4*)td;
        const int4  iv = *(const int4*)(td + 4);
        const f16x4 v00 = *(const f16x4*)&vbase[iv.x];
        const f16x4 v01 = *(const f16x4*)&vbase[iv.y];
        const f16x4 v10 = *(const f16x4*)&vbase[iv.z];
        const f16x4 v11 = *(const f16x4*)&vbase[iv.w];
        acc.x += wv.x * (float)v00[0] + wv.y * (float)v01[0] + wv.z * (float)v10[0] + wv.w * (float)v11[0];
        acc.y += wv.x * (float)v00[1] + wv.y * (float)v01[1] + wv.z * (float)v10[1] + wv.w * (float)v11[1];
        acc.z += wv.x * (float)v00[2] + wv.y * (float)v01[2] + wv.z * (float)v10[2] + wv.w * (float)v11[2];
        acc.w += wv.x * (float)v00[3] + wv.y * (float)v01[3] + wv.z * (float)v10[3] + wv.w * (float)v11[3];
    }

    f16x4 o;
    o.x = (_Float16)acc.x; o.y = (_Float16)acc.y;
    o.z = (_Float16)acc.z; o.w = (_Float16)acc.w;
    *(f16x4*)&outv[(size_t)qi * 256 + m * 32 + d4 * 4] = o;
}

// ---------------- launch ----------------
extern "C" void kernel_launch(void* const* d_in, const int* in_sizes, int n_in,
                              void* d_out, int out_size, void* d_ws, size_t ws_size,
                              hipStream_t stream)
{
    const float* query         = (const float*)d_in[0];
    const float* input_flatten = (const float*)d_in[2];
    const float* W_off  = (const float*)d_in[5];
    const float* b_off  = (const float*)d_in[6];
    const float* W_attn = (const float*)d_in[7];
    const float* b_attn = (const float*)d_in[8];
    const float* W_val  = (const float*)d_in[9];
    const float* b_val  = (const float*)d_in[10];
    const float* W_out  = (const float*)d_in[11];
    const float* b_out  = (const float*)d_in[12];
    float* out = (float*)d_out;

    // Workspace (~84 MB peak). Region1 (22.3 MB @ 0) is time-shared
    // under the launch ORDER below (stream-serial => disjoint lifetimes):
    //   IFf16 (22.3 MB): written by split, consumed by value GEMM
    //   Qf16  (16.8 MB): written after value GEMM, consumed by offattn GEMM
    //   Sf16  (16.8 MB): written by sampler, consumed by out GEMM
    char* w = (char*)d_ws;
    _Float16* IFf16 = (_Float16*)w;
    _Float16* Qf16  = (_Float16*)w;
    _Float16* Sf16  = (_Float16*)w;
    _Float16* value16 = (_Float16*)(w + 23068672);     // 43520x256 f16 (22.3 MB)
    float*    attnbuf = (float*)(w + 67633152);        // 32768x128 f32 (16.8 MB)
    _Float16* Wvt = (_Float16*)(w + 84410368);         // [256][256] f16
    _Float16* Wot = Wvt + 65536;                       // [256][256] f16
    _Float16* Wct = Wot + 65536;                       // [384][256] f16 (off|attn)
    float* offbuf = out;   // off staged in d_out, consumed before final GEMM

    dim3 blk(256);

    // weight transforms (tiny)
    tsplit_f16_kernel<<<256, blk, 0, stream>>>(W_val, Wvt, 256);
    tsplit_f16_kernel<<<256, blk, 0, stream>>>(W_out, Wot, 256);
    tsplit_f16_kernel<<<256, blk, 0, stream>>>(W_off, Wct, 256);
    tsplit_f16_kernel<<<128, blk, 0, stream>>>(W_attn, Wct + 65536, 128);

    // 1) IF -> f16; value(f16) = IF @ W_val + b_val  (f16 taps halve L2 gather bytes)
    split_f16_kernel<<<(1392640 + 255) / 256, blk, 0, stream>>>(input_flatten, IFf16, 1392640);
    gemm_f16<true><<<dim3(2, 340), blk, 0, stream>>>(
        IFf16, Wvt, b_val, b_val, value16, value16, 43520, 256, 256, 256);

    // 2) query -> f16; fused off|attn GEMM (routed epilogue, f32 out)
    split_f16_kernel<<<(1048576 + 255) / 256, blk, 0, stream>>>(query, Qf16, 1048576);
    gemm_f16<false><<<dim3(3, 256), blk, 0, stream>>>(
        Qf16, Wct, b_off, b_attn, offbuf, attnbuf, 32768, 384, 256, 256);

    // 3) softmax over 16 per (n,lq,m)
    softmax16_kernel<<<1024, blk, 0, stream>>>(attnbuf, 262144);

    // 4) sampling: f16 taps -> f16 sampled
    sample_kernel_v7<<<8192, blk, 0, stream>>>(value16, offbuf, attnbuf, Sf16);

    // 5) out = sampled @ W_out + b_out (f16 MFMA, f32 out)
    gemm_f16<false><<<dim3(2, 256), blk, 0, stream>>>(
        Sf16, Wot, b_out, b_out, out, out, 32768, 256, 256, 256);
}

// Round 2
// 253.952 us; speedup vs baseline: 1.0960x; 1.0761x over previous
//
#include <hip/hip_runtime.h>
#include <math.h>

// Problem constants (fixed by reference file)
#define NB   2
#define LQ   16384
#define CDIM 256
#define MH   8          // heads
#define DH   32         // head dim
#define LIN  21760      // 128^2+64^2+32^2+16^2
#define NPIX (NB * LIN) // 43520 total pixels across batch

typedef __attribute__((ext_vector_type(8))) _Float16 f16x8;
typedef __attribute__((ext_vector_type(4))) _Float16 f16x4;
typedef __attribute__((ext_vector_type(4))) float    f32x4;

// async 16B global->LDS (wave-uniform LDS base + lane*16 — no padding allowed)
__device__ __forceinline__ void async16(const void* g, void* l) {
    __builtin_amdgcn_global_load_lds(
        (const __attribute__((address_space(1))) void*)g,
        (__attribute__((address_space(3))) void*)l,
        16, 0, 0);
}

// ---------------- merged weight transposes: W[k][n] f32 -> t[n][k] f16 ----------
// r in [0,896): 0-255 Wvt (W_val), 256-511 Wot (W_out),
//               512-767 Wct rows 0-255 (W_off), 768-895 Wct rows 256-383 (W_attn)
__global__ __launch_bounds__(256) void tsplit_all_kernel(
    const float* __restrict__ Wv, const float* __restrict__ Wo,
    const float* __restrict__ Wf, const float* __restrict__ Wa,
    _Float16* __restrict__ Wvt, _Float16* __restrict__ Wot, _Float16* __restrict__ Wct)
{
    const int i = blockIdx.x * 256 + threadIdx.x;   // 896*256 exact
    const int r = i >> 8;
    const int kk = i & 255;
    if (r < 256) {
        Wvt[r * 256 + kk] = (_Float16)Wv[kk * 256 + r];
    } else if (r < 512) {
        const int n = r - 256;
        Wot[n * 256 + kk] = (_Float16)Wo[kk * 256 + n];
    } else if (r < 768) {
        const int n = r - 512;
        Wct[n * 256 + kk] = (_Float16)Wf[kk * 256 + n];
    } else {
        const int n = r - 768;
        Wct[(256 + n) * 256 + kk] = (_Float16)Wa[kk * 128 + n];
    }
}

// ---------------- single-term f16 MFMA GEMM, routed epilogue ----------------
// C = A @ B + bias. A: MxK row-major (f32 if A_F32 — converted in-kernel — else f16).
// Bt: [N][K] f16 (pre-transposed). Tile 128x128x32, 256 threads.
// Output routing: cols < N0 -> C0 (ld N0, bias0); cols >= N0 -> C1 (ld N-N0, bias1).
// OUT_MODE: 0 = f32 flat, 1 = f16 flat, 2 = f16 head-major value layout
//           (dst[(col>>5)*NPIX + row][col&31], for the sampler's line locality).
template <int OUT_MODE, bool A_F32>
__global__ __launch_bounds__(256) void gemm_f16(
    const void* __restrict__ Araw, const _Float16* __restrict__ Bt,
    const float* __restrict__ bias0, const float* __restrict__ bias1,
    void* __restrict__ C0, void* __restrict__ C1,
    int M, int N, int K, int N0)
{
    __shared__ __align__(16) char AshRaw[A_F32 ? 128 * 32 * 4 : 128 * 32 * 2];
    __shared__ _Float16 Bsh[128 * 32];   // [n][k], unpadded (global_load_lds)

    const int tid  = threadIdx.x;
    const int wave = tid >> 6, lane = tid & 63;
    const int quad = lane >> 4, l16 = lane & 15;
    const int bm = blockIdx.y * 128;
    const int bn = blockIdx.x * 128;
    const int wrow = wave * 32;

    f32x4 acc[2][8] = {};

    const int s0 = tid,        row0 = s0 >> 2, kg0 = (s0 & 3) << 3;
    const int s1 = tid + 256,  row1 = s1 >> 2, kg1 = (s1 & 3) << 3;

    for (int k0 = 0; k0 < K; k0 += 32) {
        if (A_F32) {
            const float* A = (const float*)Araw;
            float* AshF = (float*)AshRaw;
            #pragma unroll
            for (int j = 0; j < 4; ++j) {
                const int s = tid + 256 * j;
                async16(A + (size_t)(bm + (s >> 3)) * K + k0 + ((s & 7) << 2),
                        AshF + s * 4);
            }
        } else {
            const _Float16* A = (const _Float16*)Araw;
            _Float16* Ash = (_Float16*)AshRaw;
            async16(A + (size_t)(bm + row0) * K + k0 + kg0, Ash + s0 * 8);
            async16(A + (size_t)(bm + row1) * K + k0 + kg1, Ash + s1 * 8);
        }
        async16(Bt + (size_t)(bn + row0) * K + k0 + kg0, Bsh + s0 * 8);
        async16(Bt + (size_t)(bn + row1) * K + k0 + kg1, Bsh + s1 * 8);
        __syncthreads();

        f16x8 ah[2];
        #pragma unroll
        for (int r = 0; r < 2; ++r) {
            if (A_F32) {
                const float* AshF = (const float*)AshRaw;
                const float* ap = &AshF[(wrow + r * 16 + l16) * 32 + quad * 8];
                const f32x4 a0 = *(const f32x4*)ap;
                const f32x4 a1 = *(const f32x4*)(ap + 4);
                f16x8 h;
                h[0] = (_Float16)a0[0]; h[1] = (_Float16)a0[1];
                h[2] = (_Float16)a0[2]; h[3] = (_Float16)a0[3];
                h[4] = (_Float16)a1[0]; h[5] = (_Float16)a1[1];
                h[6] = (_Float16)a1[2]; h[7] = (_Float16)a1[3];
                ah[r] = h;
            } else {
                const _Float16* Ash = (const _Float16*)AshRaw;
                ah[r] = *(const f16x8*)&Ash[(wrow + r * 16 + l16) * 32 + quad * 8];
            }
        }
        #pragma unroll
        for (int half = 0; half < 2; ++half) {
            f16x8 bh[4];
            #pragma unroll
            for (int c = 0; c < 4; ++c)
                bh[c] = *(const f16x8*)&Bsh[(half * 64 + c * 16 + l16) * 32 + quad * 8];
            #pragma unroll
            for (int r = 0; r < 2; ++r)
                #pragma unroll
                for (int c = 0; c < 4; ++c)
                    acc[r][half * 4 + c] = __builtin_amdgcn_mfma_f32_16x16x32_f16(
                        ah[r], bh[c], acc[r][half * 4 + c], 0, 0, 0);
        }
        __syncthreads();
    }

    // epilogue: C/D layout col=lane&15, row=quad*4+reg (HW-verified mapping)
    void* Cb; const float* bb; int ldc, coff;
    if (bn < N0) { Cb = C0; bb = bias0; ldc = N0;     coff = 0;  }
    else         { Cb = C1; bb = bias1; ldc = N - N0; coff = N0; }
    #pragma unroll
    for (int c = 0; c < 8; ++c) {
        const int col = bn + c * 16 + l16 - coff;
        const float bia = bb[col];
        #pragma unroll
        for (int r = 0; r < 2; ++r)
            #pragma unroll
            for (int i = 0; i < 4; ++i) {
                const int rr = bm + wrow + r * 16 + quad * 4 + i;
                const float v = acc[r][c][i] + bia;
                if (OUT_MODE == 2)
                    ((_Float16*)Cb)[((size_t)(col >> 5) * NPIX + rr) * 32 + (col & 31)] = (_Float16)v;
                else if (OUT_MODE == 1)
                    ((_Float16*)Cb)[(size_t)rr * ldc + col] = (_Float16)v;
                else
                    ((float*)Cb)[(size_t)rr * ldc + col] = v;
            }
    }
}

// ---------------- sampling v8: head-major f16 value + fused softmax ----------------
// Block = 256 threads, 4 queries.
// Phase 1: 512 tasks (q,m,pt). Reads RAW attn logits; softmax over the 16-task
//   group fused via 16-lane __shfl_xor reduce (group == 16 consecutive lanes).
//   Writes LDS: 4 combined corner weights + 4 indices.
// Phase 2: thread (q,m,d4) owns 4 channels; gathers f16x4 from the HEAD-MAJOR
//   value layout (m, pixel, 32ch): x-adjacent corners are 64 B apart -> share a
//   128 B line when x0 is even, cutting L2 line traffic ~25% (the measured
//   bottleneck: ~28 TB/s of line-granular L2->L1 reads).
// Reference quirk preserved: sample (l,p) weighted by attn[..., p, l].
__global__ __launch_bounds__(256) void sample_kernel_v8(
    const _Float16* __restrict__ value,  // (MH, NPIX, 32) f16 head-major
    const float* __restrict__ off,       // (N*LQ, 256)
    const float* __restrict__ attn,      // (N*LQ, 128) RAW logits
    _Float16* __restrict__ outv)
{
    __shared__ __align__(16) float lds_task[8][516];

    const int tid = threadIdx.x;
    const int qbase = blockIdx.x * 4;

    #pragma unroll
    for (int j = 0; j < 2; ++j) {
        const int t  = tid + 256 * j;
        const int q  = t >> 7;
        const int m  = (t >> 4) & 7;
        const int pt = t & 15;          // pt = l*4 + p
        const int l  = pt >> 2;
        const int p  = pt & 3;
        const int qi = qbase + q;
        const int lq = qi & (LQ - 1);
        const int n  = qi >> 14;

        const int Hl = 128 >> l;
        const int STARTS[4] = {0, 16384, 20480, 21504};

        const float2 oxy = *(const float2*)&off[(size_t)qi * 256 + m * 32 + pt * 2];

        // fused softmax over the 16 logits of this (q,m) group.
        // group == 16 consecutive lanes; cols m*16 + p*4 + l hit each of the
        // 16 columns exactly once across the group (bijection), so the group
        // reduce IS the softmax denominator. Transposed pairing preserved.
        const float logit = attn[(size_t)qi * 128 + m * 16 + p * 4 + l];
        float mx = logit;
        #pragma unroll
        for (int d = 1; d < 16; d <<= 1) mx = fmaxf(mx, __shfl_xor(mx, d, 16));
        const float e = __expf(logit - mx);
        float sm = e;
        #pragma unroll
        for (int d = 1; d < 16; d <<= 1) sm += __shfl_xor(sm, d, 16);
        const float w = e / sm;

        const float refx = ((lq & 127) + 0.5f) * (1.0f / 128.0f);
        const float refy = ((lq >> 7)  + 0.5f) * (1.0f / 128.0f);

        const float x = refx * (float)Hl + oxy.x - 0.5f;
        const float y = refy * (float)Hl + oxy.y - 0.5f;
        const float x0f = floorf(x), y0f = floorf(y);
        const int x0 = (int)x0f, y0 = (int)y0f;
        const int x1 = x0 + 1,  y1 = y0 + 1;
        const float fx = x - x0f, fy = y - y0f;
        const float gx = 1.f - fx, gy = 1.f - fy;

        const float vx0 = (x0 >= 0 && x0 < Hl) ? 1.f : 0.f;
        const float vx1 = (x1 >= 0 && x1 < Hl) ? 1.f : 0.f;
        const float vy0 = (y0 >= 0 && y0 < Hl) ? 1.f : 0.f;
        const float vy1 = (y1 >= 0 && y1 < Hl) ? 1.f : 0.f;

        const int x0c = min(max(x0, 0), Hl - 1);
        const int x1c = min(max(x1, 0), Hl - 1);
        const int y0c = min(max(y0, 0), Hl - 1);
        const int y1c = min(max(y1, 0), Hl - 1);

        // head-major: base in f16 elems; pixel stride 32
        const int base = m * (NPIX * 32) + (n * LIN + STARTS[l]) * 32;
        const int i00 = base + (y0c * Hl + x0c) * 32;
        const int i01 = base + (y0c * Hl + x1c) * 32;
        const int i10 = base + (y1c * Hl + x0c) * 32;
        const int i11 = base + (y1c * Hl + x1c) * 32;

        float4 wv;
        wv.x = w * gy * gx * vy0 * vx0;
        wv.y = w * gy * fx * vy0 * vx1;
        wv.z = w * fy * gx * vy1 * vx0;
        wv.w = w * fy * fx * vy1 * vx1;

        float* dst = &lds_task[m][(q * 16 + pt) * 8];
        *(float4*)dst = wv;
        int4 iv = {i00, i01, i10, i11};
        *(int4*)(dst + 4) = iv;
    }
    __syncthreads();

    // ---- Phase 2: gather f16 taps + weighted accumulate ----
    const int q  = tid >> 6;
    const int m  = (tid >> 3) & 7;
    const int d4 = tid & 7;
    const int qi = qbase + q;

    const _Float16* vbase = value + d4 * 4;

    float4 acc = {0.f, 0.f, 0.f, 0.f};
    #pragma unroll
    for (int pt = 0; pt < 16; ++pt) {
        const float* td = &lds_task[m][(q * 16 + pt) * 8];
        const float4 wv = *(const float4*)td;
        const int4  iv = *(const int4*)(td + 4);
        const f16x4 v00 = *(const f16x4*)&vbase[iv.x];
        const f16x4 v01 = *(const f16x4*)&vbase[iv.y];
        const f16x4 v10 = *(const f16x4*)&vbase[iv.z];
        const f16x4 v11 = *(const f16x4*)&vbase[iv.w];
        acc.x += wv.x * (float)v00[0] + wv.y * (float)v01[0] + wv.z * (float)v10[0] + wv.w * (float)v11[0];
        acc.y += wv.x * (float)v00[1] + wv.y * (float)v01[1] + wv.z * (float)v10[1] + wv.w * (float)v11[1];
        acc.z += wv.x * (float)v00[2] + wv.y * (float)v01[2] + wv.z * (float)v10[2] + wv.w * (float)v11[2];
        acc.w += wv.x * (float)v00[3] + wv.y * (float)v01[3] + wv.z * (float)v10[3] + wv.w * (float)v11[3];
    }

    f16x4 o;
    o.x = (_Float16)acc.x; o.y = (_Float16)acc.y;
    o.z = (_Float16)acc.z; o.w = (_Float16)acc.w;
    *(f16x4*)&outv[(size_t)qi * 256 + m * 32 + d4 * 4] = o;
}

// ---------------- launch ----------------
extern "C" void kernel_launch(void* const* d_in, const int* in_sizes, int n_in,
                              void* d_out, int out_size, void* d_ws, size_t ws_size,
                              hipStream_t stream)
{
    const float* query         = (const float*)d_in[0];
    const float* input_flatten = (const float*)d_in[2];
    const float* W_off  = (const float*)d_in[5];
    const float* b_off  = (const float*)d_in[6];
    const float* W_attn = (const float*)d_in[7];
    const float* b_attn = (const float*)d_in[8];
    const float* W_val  = (const float*)d_in[9];
    const float* b_val  = (const float*)d_in[10];
    const float* W_out  = (const float*)d_in[11];
    const float* b_out  = (const float*)d_in[12];
    float* out = (float*)d_out;

    // Workspace (~84 MB peak). Region1 (16.8 MB @ 0):
    //   Sf16: written by sampler, consumed by out GEMM (splits eliminated —
    //   f32->f16 conversion fused into the GEMM A-path).
    char* w = (char*)d_ws;
    _Float16* Sf16 = (_Float16*)w;
    _Float16* value16 = (_Float16*)(w + 23068672);     // (8, 43520, 32) f16 head-major (22.3 MB)
    float*    attnbuf = (float*)(w + 67633152);        // 32768x128 f32 raw logits (16.8 MB)
    _Float16* Wvt = (_Float16*)(w + 84410368);         // [256][256] f16
    _Float16* Wot = Wvt + 65536;                       // [256][256] f16
    _Float16* Wct = Wot + 65536;                       // [384][256] f16 (off|attn)
    float* offbuf = out;   // off staged in d_out, consumed before final GEMM

    dim3 blk(256);

    // weight transforms (one merged launch)
    tsplit_all_kernel<<<896, blk, 0, stream>>>(W_val, W_out, W_off, W_attn, Wvt, Wot, Wct);

    // 1) value(f16, head-major) = IF(f32) @ W_val + b_val (in-GEMM conversion)
    gemm_f16<2, true><<<dim3(2, 340), blk, 0, stream>>>(
        input_flatten, Wvt, b_val, b_val, value16, value16, 43520, 256, 256, 256);

    // 2) fused off|attn GEMM on query f32 (routed epilogue, f32 out; attn = raw logits)
    gemm_f16<0, true><<<dim3(3, 256), blk, 0, stream>>>(
        query, Wct, b_off, b_attn, offbuf, attnbuf, 32768, 384, 256, 256);

    // 3) sampling: fused softmax + f16 head-major taps -> f16 sampled
    sample_kernel_v8<<<8192, blk, 0, stream>>>(value16, offbuf, attnbuf, Sf16);

    // 4) out = sampled @ W_out + b_out (f16 MFMA, f32 out)
    gemm_f16<0, false><<<dim3(2, 256), blk, 0, stream>>>(
        Sf16, Wot, b_out, b_out, out, out, 32768, 256, 256, 256);
}